// Round 2
// baseline (383.680 us; speedup 1.0000x reference)
//
#include <hip/hip_runtime.h>
#include <math.h>

#define NC 19
#define NB 8
#define HW (512 * 512)
#define CHUNKS 16
#define NG 10      // channel pairs {0,1},...,{16,17}, then {18, counts}
#define TPB 256
#define STRIDE 39  // odd stride in floats: tid*39 covers all 32 banks (gcd(39,32)=1)
#define UNROLL 4   // software-pipeline batch: load 4 iters ahead
#define FT 1024
#define NBLK (NG * CHUNKS * NB)  // 1280 blocks; 1280 % 8 == 0 -> bijective XCD swizzle

typedef float v4f __attribute__((ext_vector_type(4)));
typedef int v4i __attribute__((ext_vector_type(4)));

// LDS accumulate: ds_add_f32 (atomic fadd, no return). Replaces the
// ds_read+wait+v_add+ds_write RMW chain -- the compiler cannot prove
// t.x != t.y (random labels DO alias ~1/19), so the += form serialized into a
// ~16-link LDS latency chain per superstep. The atomic is fire-and-forget:
// hardware resolves aliasing, no lgkmcnt waits, half the ds instructions.
#define LDS_ADD(p, v) \
    (void)__hip_atomic_fetch_add((p), (v), __ATOMIC_RELAXED, __HIP_MEMORY_SCOPE_WORKGROUP)

// Workspace: S_part[NB][CHUNKS][NC][20] floats (194,560 B), unique slot per
// (b,chunk,col) -> no zero-init, no atomics. Row t = class, col c in 0..18 =
// sum of channel c over class-t pixels, col 19 = class-t count.

__global__ __launch_bounds__(TPB) void accum_kernel(const float* __restrict__ seg,
                                                    const int* __restrict__ tgt,
                                                    float* __restrict__ S_part) {
    // Per-thread PRIVATE bins, scalar f32, odd stride (conflict-free, R3/R6-proven).
    // 39*4B*256 = 39.9 KB -> 4 blocks/CU resident, 1280 blocks = 5 per CU exactly.
    __shared__ float bins[TPB * STRIDE];

    const int tid = threadIdx.x;

    // XCD-tile swizzle (R1: ~-2.6us, kept): blocks sharing one tgt chunk land on
    // ONE XCD so the chunk is pulled into that L2 once, not 8x from L3.
    const int bid = blockIdx.x;
    const int L = (bid & 7) * (NBLK / 8) + (bid >> 3);  // bijective, 1280 % 8 == 0
    const int g = L % NG;                                // group: fastest within tile
    const int tile = L / NG;                             // 0..127 = (b, chunk)
    const int chunk = tile & (CHUNKS - 1);
    const int b = tile >> 4;                             // CHUNKS == 16

    const bool last = (g == NG - 1);
    const int c0 = 2 * g;

    float* p0 = &bins[tid * STRIDE];
    float* p1 = p0 + NC;
    #pragma unroll
    for (int k = 0; k < STRIDE; ++k) p0[k] = 0.0f;
    // Rows are thread-private until the fold: no barrier needed here.

    const int per_chunk = HW / CHUNKS;  // 16384 pixels
    const size_t pix = (size_t)chunk * per_chunk;
    const v4f* __restrict__ s0 = (const v4f*)(seg + ((size_t)(b * NC + c0)) * HW + pix);
    // Last group: alias s1 to s0 so every issued load is in-bounds even if the
    // compiler if-converts the select below (c0+1 == 19 would read past seg at b==7).
    const v4f* __restrict__ s1 =
        (const v4f*)(seg + ((size_t)(b * NC + (last ? c0 : c0 + 1))) * HW + pix);
    const v4i* __restrict__ tv = (const v4i*)(tgt + (size_t)b * HW + pix);

    const int iters = per_chunk / 4 / TPB;   // 16
    const int nsuper = iters / UNROLL;       // 4
    const v4f ones = {1.0f, 1.0f, 1.0f, 1.0f};

    // Cacheable loads on purpose: harness restores d_in before every replay, so
    // seg+tgt are L3-warm (R5 evidence: 6.2 MB-FETCH replays). nt would forfeit it.
    v4f A0[UNROLL], A1[UNROLL];
    v4i T[UNROLL];
    #pragma unroll
    for (int j = 0; j < UNROLL; ++j) {
        const int v = j * TPB + tid;
        T[j] = tv[v];
        A0[j] = s0[v];
        A1[j] = last ? ones : s1[v];
    }

    for (int s = 0; s < nsuper; ++s) {
        v4f B0[UNROLL] = {}, B1[UNROLL] = {};
        v4i TN[UNROLL] = {};
        if (s + 1 < nsuper) {
            const int base = (s + 1) * UNROLL * TPB + tid;
            #pragma unroll
            for (int j = 0; j < UNROLL; ++j) {
                const int v = base + j * TPB;
                TN[j] = tv[v];
                B0[j] = s0[v];
                B1[j] = last ? ones : s1[v];
            }
        }
        #pragma unroll
        for (int j = 0; j < UNROLL; ++j) {
            const v4i t = T[j];
            // 8 fire-and-forget ds_add_f32 per vector; no dependency chain.
            LDS_ADD(&p0[t.x], A0[j].x);  LDS_ADD(&p1[t.x], A1[j].x);
            LDS_ADD(&p0[t.y], A0[j].y);  LDS_ADD(&p1[t.y], A1[j].y);
            LDS_ADD(&p0[t.z], A0[j].z);  LDS_ADD(&p1[t.z], A1[j].z);
            LDS_ADD(&p0[t.w], A0[j].w);  LDS_ADD(&p1[t.w], A1[j].w);
        }
        #pragma unroll
        for (int j = 0; j < UNROLL; ++j) { T[j] = TN[j]; A0[j] = B0[j]; A1[j] = B1[j]; }
    }
    __syncthreads();

    // Stage 1: fold 256 rows -> 32 rows over the 38 live columns, in-place safe.
    for (int e = tid; e < 32 * 2 * NC; e += TPB) {  // 1216 elements
        const int r = e & 31, c = e >> 5;  // c in 0..37
        float acc = bins[r * STRIDE + c];
        #pragma unroll
        for (int j = 1; j < TPB / 32; ++j) acc += bins[(r + 32 * j) * STRIDE + c];
        bins[r * STRIDE + c] = acc;
    }
    __syncthreads();

    // Stage 2: 38 lanes (wave 0) sum the 32 rows of their column; plain store
    // to this block's unique slots.
    if (tid < 2 * NC) {
        float acc = bins[tid];
        #pragma unroll
        for (int r = 1; r < 32; ++r) acc += bins[r * STRIDE + tid];
        const int t = (tid < NC) ? tid : tid - NC;        // class
        const int c = (tid < NC) ? c0 : c0 + 1;           // channel col; g=9,hi -> 19 = counts
        S_part[(((size_t)(b * CHUNKS + chunk)) * NC + t) * 20 + c] = acc;
    }
}

__global__ __launch_bounds__(FT) void finalize_kernel(const float* __restrict__ S_part,
                                                      float* __restrict__ out) {
    __shared__ float S[NB * NC * 20];  // 3040 floats: S[b][t][c], col 19 = count
    __shared__ float wsum[FT / 64];
    const int tid = threadIdx.x;

    // Phase A: reduce the 16 chunk partials (coalesced: r is contiguous).
    for (int e = tid; e < NB * NC * 20; e += FT) {
        const int b = e / (NC * 20);
        const int r = e - b * NC * 20;
        float a = 0.0f;
        #pragma unroll
        for (int ch = 0; ch < CHUNKS; ++ch)
            a += S_part[((size_t)(b * CHUNKS + ch)) * (NC * 20) + r];
        S[e] = a;
    }
    __syncthreads();

    // Phase B: 2888 log terms.
    const float eps = 2.220446049250313e-16f;  // np.spacing(1)
    float local = 0.0f;
    for (int idx = tid; idx < NB * NC * NC; idx += FT) {
        const int b = idx / (NC * NC);
        const int r = idx - b * NC * NC;
        const int i = r / NC;
        const int k = r - i * NC;
        const float* Sb = S + b * NC * 20;
        const float cnt_i = Sb[i * 20 + 19];
        const float cnt_k = Sb[k * 20 + 19];
        const float alpha = (cnt_i > 0.0f) ? Sb[i * 20 + i] / cnt_i : 0.0f;
        const float beta = (cnt_k > 0.0f) ? 1.0f - Sb[k * 20 + i] / cnt_k : 0.0f;
        local += logf(0.5f * (alpha + beta + eps));
    }

    #pragma unroll
    for (int off = 32; off > 0; off >>= 1) local += __shfl_down(local, off);
    if ((tid & 63) == 0) wsum[tid >> 6] = local;
    __syncthreads();
    if (tid == 0) {
        float t = 0.0f;
        #pragma unroll
        for (int w = 0; w < FT / 64; ++w) t += wsum[w];
        out[0] = -0.5f * t / (float)NB;
    }
}

extern "C" void kernel_launch(void* const* d_in, const int* in_sizes, int n_in,
                              void* d_out, int out_size, void* d_ws, size_t ws_size,
                              hipStream_t stream) {
    const float* seg = (const float*)d_in[0];
    const int* tgt = (const int*)d_in[1];
    float* S_part = (float*)d_ws;  // 194,560 B; every slot written unconditionally

    dim3 grid(NBLK);  // 1D; XCD-tile swizzle done in-kernel
    accum_kernel<<<grid, TPB, 0, stream>>>(seg, tgt, S_part);
    finalize_kernel<<<1, FT, 0, stream>>>(S_part, (float*)d_out);
}

// Round 3
// 233.392 us; speedup vs baseline: 1.6439x; 1.6439x over previous
//
#include <hip/hip_runtime.h>
#include <math.h>

#define NC 19
#define NB 8
#define HW (512 * 512)
#define CHUNKS 16
#define NG 10      // channel pairs {0,1},...,{16,17}, then {18, counts}
#define TPB 128    // R3: 128 threads -> 19.9 KB LDS -> 8 blocks/CU -> all 1280
                   // blocks co-resident (capacity 2048), no dispatch tail.
#define STRIDE 39  // odd stride in floats: tid*39 covers all 32 banks (gcd(39,32)=1)
#define UNROLL 4   // software-pipeline batch: load 4 iters ahead
#define FT 1024
#define NBLK (NG * CHUNKS * NB)  // 1280 blocks; 1280 % 8 == 0 -> bijective XCD swizzle

typedef float v4f __attribute__((ext_vector_type(4)));
typedef int v4i __attribute__((ext_vector_type(4)));

// R2 post-mortem: ds_add_f32 LDS atomics were 5.5x SLOWER than the plain
// ds_read+v_add+ds_write RMW chain (220us vs ~40us, zero bank conflicts both
// ways) -- gfx950's LDS atomic-fadd path has far lower throughput than the
// pipelined read/write path. Keep the RMW form.

// Workspace: S_part[NB][CHUNKS][NC][20] floats (194,560 B), unique slot per
// (b,chunk,col) -> no zero-init, no atomics. Row t = class, col c in 0..18 =
// sum of channel c over class-t pixels, col 19 = class-t count.

__global__ __launch_bounds__(TPB) void accum_kernel(const float* __restrict__ seg,
                                                    const int* __restrict__ tgt,
                                                    float* __restrict__ S_part) {
    // Per-thread PRIVATE bins, scalar f32, odd stride (conflict-free, R3/R6-proven).
    // 128*39*4B = 19,968 B -> 8 blocks/CU by LDS, 16 waves/CU -- same wave
    // occupancy as the 256-thread version but every block resident at once.
    __shared__ float bins[TPB * STRIDE];

    const int tid = threadIdx.x;

    // XCD-tile swizzle (R1: small win, kept): blocks sharing one tgt chunk land
    // on ONE XCD so the chunk is pulled into that L2 once, not 8x from L3.
    const int bid = blockIdx.x;
    const int L = (bid & 7) * (NBLK / 8) + (bid >> 3);  // bijective, 1280 % 8 == 0
    const int g = L % NG;                                // group: fastest within tile
    const int tile = L / NG;                             // 0..127 = (b, chunk)
    const int chunk = tile & (CHUNKS - 1);
    const int b = tile >> 4;                             // CHUNKS == 16

    const bool last = (g == NG - 1);
    const int c0 = 2 * g;

    float* p0 = &bins[tid * STRIDE];
    float* p1 = p0 + NC;
    #pragma unroll
    for (int k = 0; k < STRIDE; ++k) p0[k] = 0.0f;
    // Rows are thread-private until the fold: no barrier needed here.

    const int per_chunk = HW / CHUNKS;  // 16384 pixels
    const size_t pix = (size_t)chunk * per_chunk;
    const v4f* __restrict__ s0 = (const v4f*)(seg + ((size_t)(b * NC + c0)) * HW + pix);
    // Last group: alias s1 to s0 so every issued load is in-bounds even if the
    // compiler if-converts the select below (c0+1 == 19 would read past seg at b==7).
    const v4f* __restrict__ s1 =
        (const v4f*)(seg + ((size_t)(b * NC + (last ? c0 : c0 + 1))) * HW + pix);
    const v4i* __restrict__ tv = (const v4i*)(tgt + (size_t)b * HW + pix);

    const int iters = per_chunk / 4 / TPB;   // 32
    const int nsuper = iters / UNROLL;       // 8
    const v4f ones = {1.0f, 1.0f, 1.0f, 1.0f};

    // Cacheable loads on purpose: harness restores d_in before every replay, so
    // seg+tgt are partially L3-warm (R2 accum profile: 82 MB HBM fetch of the
    // 168 MB read). nt would forfeit the cached half.
    v4f A0[UNROLL], A1[UNROLL];
    v4i T[UNROLL];
    #pragma unroll
    for (int j = 0; j < UNROLL; ++j) {
        const int v = j * TPB + tid;
        T[j] = tv[v];
        A0[j] = s0[v];
        A1[j] = last ? ones : s1[v];
    }

    for (int s = 0; s < nsuper; ++s) {
        v4f B0[UNROLL] = {}, B1[UNROLL] = {};
        v4i TN[UNROLL] = {};
        if (s + 1 < nsuper) {
            const int base = (s + 1) * UNROLL * TPB + tid;
            #pragma unroll
            for (int j = 0; j < UNROLL; ++j) {
                const int v = base + j * TPB;
                TN[j] = tv[v];
                B0[j] = s0[v];
                B1[j] = last ? ones : s1[v];
            }
        }
        #pragma unroll
        for (int j = 0; j < UNROLL; ++j) {
            const v4i t = T[j];
            // Two independent 4-deep LDS RMW chains (channel c0 / channel c1-or-count).
            p0[t.x] += A0[j].x;  p1[t.x] += A1[j].x;
            p0[t.y] += A0[j].y;  p1[t.y] += A1[j].y;
            p0[t.z] += A0[j].z;  p1[t.z] += A1[j].z;
            p0[t.w] += A0[j].w;  p1[t.w] += A1[j].w;
        }
        #pragma unroll
        for (int j = 0; j < UNROLL; ++j) { T[j] = TN[j]; A0[j] = B0[j]; A1[j] = B1[j]; }
    }
    __syncthreads();

    // Stage 1: fold 128 rows -> 32 rows over the 38 live columns, in-place safe.
    for (int e = tid; e < 32 * 2 * NC; e += TPB) {  // 1216 elements
        const int r = e & 31, c = e >> 5;  // c in 0..37
        float acc = bins[r * STRIDE + c];
        #pragma unroll
        for (int j = 1; j < TPB / 32; ++j) acc += bins[(r + 32 * j) * STRIDE + c];
        bins[r * STRIDE + c] = acc;
    }
    __syncthreads();

    // Stage 2: 38 lanes (wave 0) sum the 32 rows of their column; plain store
    // to this block's unique slots.
    if (tid < 2 * NC) {
        float acc = bins[tid];
        #pragma unroll
        for (int r = 1; r < 32; ++r) acc += bins[r * STRIDE + tid];
        const int t = (tid < NC) ? tid : tid - NC;        // class
        const int c = (tid < NC) ? c0 : c0 + 1;           // channel col; g=9,hi -> 19 = counts
        S_part[(((size_t)(b * CHUNKS + chunk)) * NC + t) * 20 + c] = acc;
    }
}

__global__ __launch_bounds__(FT) void finalize_kernel(const float* __restrict__ S_part,
                                                      float* __restrict__ out) {
    __shared__ float S[NB * NC * 20];  // 3040 floats: S[b][t][c], col 19 = count
    __shared__ float wsum[FT / 64];
    const int tid = threadIdx.x;

    // Phase A: reduce the 16 chunk partials (coalesced: r is contiguous).
    for (int e = tid; e < NB * NC * 20; e += FT) {
        const int b = e / (NC * 20);
        const int r = e - b * NC * 20;
        float a = 0.0f;
        #pragma unroll
        for (int ch = 0; ch < CHUNKS; ++ch)
            a += S_part[((size_t)(b * CHUNKS + ch)) * (NC * 20) + r];
        S[e] = a;
    }
    __syncthreads();

    // Phase B: 2888 log terms.
    const float eps = 2.220446049250313e-16f;  // np.spacing(1)
    float local = 0.0f;
    for (int idx = tid; idx < NB * NC * NC; idx += FT) {
        const int b = idx / (NC * NC);
        const int r = idx - b * NC * NC;
        const int i = r / NC;
        const int k = r - i * NC;
        const float* Sb = S + b * NC * 20;
        const float cnt_i = Sb[i * 20 + 19];
        const float cnt_k = Sb[k * 20 + 19];
        const float alpha = (cnt_i > 0.0f) ? Sb[i * 20 + i] / cnt_i : 0.0f;
        const float beta = (cnt_k > 0.0f) ? 1.0f - Sb[k * 20 + i] / cnt_k : 0.0f;
        local += logf(0.5f * (alpha + beta + eps));
    }

    #pragma unroll
    for (int off = 32; off > 0; off >>= 1) local += __shfl_down(local, off);
    if ((tid & 63) == 0) wsum[tid >> 6] = local;
    __syncthreads();
    if (tid == 0) {
        float t = 0.0f;
        #pragma unroll
        for (int w = 0; w < FT / 64; ++w) t += wsum[w];
        out[0] = -0.5f * t / (float)NB;
    }
}

extern "C" void kernel_launch(void* const* d_in, const int* in_sizes, int n_in,
                              void* d_out, int out_size, void* d_ws, size_t ws_size,
                              hipStream_t stream) {
    const float* seg = (const float*)d_in[0];
    const int* tgt = (const int*)d_in[1];
    float* S_part = (float*)d_ws;  // 194,560 B; every slot written unconditionally

    dim3 grid(NBLK);  // 1D; XCD-tile swizzle done in-kernel
    accum_kernel<<<grid, TPB, 0, stream>>>(seg, tgt, S_part);
    finalize_kernel<<<1, FT, 0, stream>>>(S_part, (float*)d_out);
}

// Round 4
// 232.626 us; speedup vs baseline: 1.6493x; 1.0033x over previous
//
#include <hip/hip_runtime.h>
#include <math.h>

#define NC 19
#define NB 8
#define HW (512 * 512)
#define CHUNKS 16
#define NG 10      // channel pairs {0,1},...,{16,17}, then {18, counts}
#define TPB 128    // 19.5 KB LDS -> 8 blocks/CU -> all 1280 blocks co-resident
#define SROW 38    // packed v2f row: 19 classes x 2 floats; even -> 8B-aligned b64,
                   // bank stride 6 mod 32 (gcd 2) -> free 2-way alias (m136)
#define UNROLL 4   // software-pipeline batch: load 4 iters ahead
#define FT 1024
#define NBLK (NG * CHUNKS * NB)  // 1280 blocks; 1280 % 8 == 0 -> bijective XCD swizzle

typedef float v4f __attribute__((ext_vector_type(4)));
typedef float v2f __attribute__((ext_vector_type(2)));
typedef int v4i __attribute__((ext_vector_type(4)));

// R2 post-mortem: ds_add_f32 LDS atomics were 5.5x SLOWER than plain RMW
// (gfx950 LDS atomic-fadd path has far lower throughput). Keep RMW form.
// R4: pack {channel c0, channel c1} per class as one v2f -> ds_read_b64 +
// v_pk_add_f32 + ds_write_b64: HALF the DS instructions and adds per pixel.
// Ping-pong prefetch buffers (outer x2 unroll) kills the 48-mov copy loop.

// Workspace: S_part[NB][CHUNKS][NC][20] floats (194,560 B), unique slot per
// (b,chunk,col) -> no zero-init, no atomics. Row t = class, col c in 0..18 =
// sum of channel c over class-t pixels, col 19 = class-t count.

__global__ __launch_bounds__(TPB) void accum_kernel(const float* __restrict__ seg,
                                                    const int* __restrict__ tgt,
                                                    float* __restrict__ S_part) {
    __shared__ float bins[TPB * SROW];  // 19,456 B, per-thread-private rows

    const int tid = threadIdx.x;

    // XCD-tile swizzle (R1, kept): blocks sharing one tgt chunk land on ONE XCD.
    const int bid = blockIdx.x;
    const int L = (bid & 7) * (NBLK / 8) + (bid >> 3);  // bijective, 1280 % 8 == 0
    const int g = L % NG;
    const int tile = L / NG;
    const int chunk = tile & (CHUNKS - 1);
    const int b = tile >> 4;                             // CHUNKS == 16

    const bool last = (g == NG - 1);
    const int c0 = 2 * g;

    v2f* pp = (v2f*)&bins[tid * SROW];   // pp[t] = {sum_c0, sum_c1} for class t
    #pragma unroll
    for (int k = 0; k < NC; ++k) pp[k] = (v2f){0.0f, 0.0f};
    // Rows are thread-private until the fold: no barrier needed here.

    const int per_chunk = HW / CHUNKS;  // 16384 pixels
    const size_t pix = (size_t)chunk * per_chunk;
    const v4f* __restrict__ s0 = (const v4f*)(seg + ((size_t)(b * NC + c0)) * HW + pix);
    // Last group: alias s1 to s0 so every issued load is in-bounds even if the
    // compiler if-converts the select below (c0+1 == 19 would read past seg at b==7).
    const v4f* __restrict__ s1 =
        (const v4f*)(seg + ((size_t)(b * NC + (last ? c0 : c0 + 1))) * HW + pix);
    const v4i* __restrict__ tv = (const v4i*)(tgt + (size_t)b * HW + pix);

    const int iters = per_chunk / 4 / TPB;   // 32
    const int nsuper = iters / UNROLL;       // 8 (even -> clean ping-pong)
    const v4f ones = {1.0f, 1.0f, 1.0f, 1.0f};

    // Cacheable loads on purpose: inputs are ~half L3-warm per replay (R2:
    // 82 MB HBM fetch of 168 MB read); nt would forfeit the cached half.
    v4f A0[UNROLL], A1[UNROLL];
    v4f B0[UNROLL], B1[UNROLL];
    v4i TA[UNROLL], TB[UNROLL];

#define PREFETCH(T_, Z0, Z1, stage)                               \
    if ((stage) < nsuper) {                                       \
        const int base_ = (stage) * UNROLL * TPB + tid;           \
        _Pragma("unroll")                                         \
        for (int j = 0; j < UNROLL; ++j) {                        \
            const int v_ = base_ + j * TPB;                       \
            T_[j] = tv[v_];                                       \
            Z0[j] = s0[v_];                                       \
            Z1[j] = last ? ones : s1[v_];                         \
        }                                                         \
    }

#define CONSUME(T_, Z0, Z1)                                       \
    _Pragma("unroll")                                             \
    for (int j = 0; j < UNROLL; ++j) {                            \
        const v4i t_ = T_[j];                                     \
        v2f u_;                                                   \
        u_.x = Z0[j].x; u_.y = Z1[j].x; pp[t_.x] += u_;           \
        u_.x = Z0[j].y; u_.y = Z1[j].y; pp[t_.y] += u_;           \
        u_.x = Z0[j].z; u_.y = Z1[j].z; pp[t_.z] += u_;           \
        u_.x = Z0[j].w; u_.y = Z1[j].w; pp[t_.w] += u_;           \
    }

    PREFETCH(TA, A0, A1, 0)
    for (int s = 0; s < nsuper; s += 2) {
        PREFETCH(TB, B0, B1, s + 1)
        CONSUME(TA, A0, A1)
        PREFETCH(TA, A0, A1, s + 2)
        CONSUME(TB, B0, B1)
    }
#undef PREFETCH
#undef CONSUME
    __syncthreads();

    // Stage 1: fold 128 rows -> 32 rows over the 38 live columns, in-place safe
    // (rows 0..31 written only by their owner after reading; rows >=32 read-only).
    for (int e = tid; e < 32 * SROW; e += TPB) {  // 1216 elements
        const int r = e & 31, c = e >> 5;  // c in 0..37
        float acc = bins[r * SROW + c];
        #pragma unroll
        for (int j = 1; j < TPB / 32; ++j) acc += bins[(r + 32 * j) * SROW + c];
        bins[r * SROW + c] = acc;
    }
    __syncthreads();

    // Stage 2: 38 lanes (wave 0) sum the 32 rows of their column; plain store.
    // Packed layout: col = 2*t + half, half 0 -> channel c0, half 1 -> c0+1
    // (for g==9, c0+1 == 19 == the counts column).
    if (tid < 2 * NC) {
        float acc = bins[tid];
        #pragma unroll
        for (int r = 1; r < 32; ++r) acc += bins[r * SROW + tid];
        const int t = tid >> 1;            // class
        const int c = c0 + (tid & 1);      // channel col
        S_part[(((size_t)(b * CHUNKS + chunk)) * NC + t) * 20 + c] = acc;
    }
}

__global__ __launch_bounds__(FT) void finalize_kernel(const float* __restrict__ S_part,
                                                      float* __restrict__ out) {
    __shared__ float S[NB * NC * 20];  // 3040 floats: S[b][t][c], col 19 = count
    __shared__ float wsum[FT / 64];
    const int tid = threadIdx.x;

    // Phase A: reduce the 16 chunk partials (coalesced: r is contiguous).
    for (int e = tid; e < NB * NC * 20; e += FT) {
        const int b = e / (NC * 20);
        const int r = e - b * NC * 20;
        float a = 0.0f;
        #pragma unroll
        for (int ch = 0; ch < CHUNKS; ++ch)
            a += S_part[((size_t)(b * CHUNKS + ch)) * (NC * 20) + r];
        S[e] = a;
    }
    __syncthreads();

    // Phase B: 2888 log terms.
    const float eps = 2.220446049250313e-16f;  // np.spacing(1)
    float local = 0.0f;
    for (int idx = tid; idx < NB * NC * NC; idx += FT) {
        const int b = idx / (NC * NC);
        const int r = idx - b * NC * NC;
        const int i = r / NC;
        const int k = r - i * NC;
        const float* Sb = S + b * NC * 20;
        const float cnt_i = Sb[i * 20 + 19];
        const float cnt_k = Sb[k * 20 + 19];
        const float alpha = (cnt_i > 0.0f) ? Sb[i * 20 + i] / cnt_i : 0.0f;
        const float beta = (cnt_k > 0.0f) ? 1.0f - Sb[k * 20 + i] / cnt_k : 0.0f;
        local += logf(0.5f * (alpha + beta + eps));
    }

    #pragma unroll
    for (int off = 32; off > 0; off >>= 1) local += __shfl_down(local, off);
    if ((tid & 63) == 0) wsum[tid >> 6] = local;
    __syncthreads();
    if (tid == 0) {
        float t = 0.0f;
        #pragma unroll
        for (int w = 0; w < FT / 64; ++w) t += wsum[w];
        out[0] = -0.5f * t / (float)NB;
    }
}

extern "C" void kernel_launch(void* const* d_in, const int* in_sizes, int n_in,
                              void* d_out, int out_size, void* d_ws, size_t ws_size,
                              hipStream_t stream) {
    const float* seg = (const float*)d_in[0];
    const int* tgt = (const int*)d_in[1];
    float* S_part = (float*)d_ws;  // 194,560 B; every slot written unconditionally

    dim3 grid(NBLK);  // 1D; XCD-tile swizzle done in-kernel
    accum_kernel<<<grid, TPB, 0, stream>>>(seg, tgt, S_part);
    finalize_kernel<<<1, FT, 0, stream>>>(S_part, (float*)d_out);
}